// Round 3
// baseline (222.699 us; speedup 1.0000x reference)
//
#include <hip/hip_runtime.h>

#define NN 8192
#define SS 256

typedef float        f4  __attribute__((ext_vector_type(4)));
typedef unsigned int ui4 __attribute__((ext_vector_type(4)));

// decay constants: float(1 - 0.001*0.02) and float(1 - 0.001)
__device__ __forceinline__ float decay_clamp(float w, bool vis) {
    const float d = vis ? 0.99998f : 0.999f;
    return fminf(fmaxf(w * d, -2.0f), 2.0f);
}

// ---------------------------------------------------------------------------
// Fast kernel: one block per row; handles every row WITHOUT an active spark.
// Self-contained spark check (reads only harness inputs). Lean registers:
// __launch_bounds__(256,8) -> <=64 VGPR, 8 blocks/CU.
// ---------------------------------------------------------------------------
__global__ __launch_bounds__(256, 8)
void fastRows(const float* __restrict__ W, const float* __restrict__ s,
              const unsigned int* __restrict__ visited, const float* __restrict__ noise,
              const int* __restrict__ spark_pos, const unsigned int* __restrict__ active,
              float* __restrict__ outW, float* __restrict__ outS, float* __restrict__ outV)
{
    const int row = blockIdx.x;
    const int tid = threadIdx.x;

    __shared__ int s_has;
    if (tid == 0) s_has = 0;
    __syncthreads();
    const bool match = (active[tid] != 0u) && (spark_pos[tid] == row);
    if (match) atomicOr(&s_has, 1);          // at most a couple of writers
    __syncthreads();
    if (s_has) return;                        // spark row: owned by sparkRows

    const size_t rowOff = (size_t)row * NN;
    const f4*  __restrict__ W4 = reinterpret_cast<const f4*>(W + rowOff);
    const ui4* __restrict__ V4 = reinterpret_cast<const ui4*>(visited + rowOff);
    const f4*  __restrict__ s4 = reinterpret_cast<const f4*>(s);
    f4* __restrict__ oW = reinterpret_cast<f4*>(outW + rowOff);
    f4* __restrict__ oV = reinterpret_cast<f4*>(outV + rowOff);

    float acc = 0.0f;
#pragma unroll
    for (int i = 0; i < 8; ++i) {
        const int idx = i * 256 + tid;                       // coalesced float4 index
        const f4  w  = __builtin_nontemporal_load(W4 + idx); // streaming, no reuse
        const ui4 v  = __builtin_nontemporal_load(V4 + idx);
        const f4  sv = s4[idx];                              // cached: reused by all blocks
        acc += w.x * (0.95f * sv.x);
        acc += w.y * (0.95f * sv.y);
        acc += w.z * (0.95f * sv.z);
        acc += w.w * (0.95f * sv.w);
        f4 ow, ov;
        ow.x = decay_clamp(w.x, v.x != 0u); ov.x = (v.x != 0u) ? 1.0f : 0.0f;
        ow.y = decay_clamp(w.y, v.y != 0u); ov.y = (v.y != 0u) ? 1.0f : 0.0f;
        ow.z = decay_clamp(w.z, v.z != 0u); ov.z = (v.z != 0u) ? 1.0f : 0.0f;
        ow.w = decay_clamp(w.w, v.w != 0u); ov.w = (v.w != 0u) ? 1.0f : 0.0f;
        __builtin_nontemporal_store(ow, oW + idx);
        __builtin_nontemporal_store(ov, oV + idx);
    }

    // s_new[row]: wave shuffle reduce, then 4 partials via LDS
    for (int off = 32; off > 0; off >>= 1) acc += __shfl_down(acc, off, 64);
    __shared__ float red[4];
    if ((tid & 63) == 0) red[tid >> 6] = acc;
    __syncthreads();
    if (tid == 0) {
        const float y = red[0] + red[1] + red[2] + red[3] + 0.05f * noise[row];
        outS[row] = 1.0f / (1.0f + expf(-y));   // never forced: forced rows are spark rows
    }
}

// ---------------------------------------------------------------------------
// Spark kernel: one block per spark; the lowest-indexed active spark of a row
// owns the row (handles all duplicates). Self-contained: reads only inputs.
// ---------------------------------------------------------------------------
__global__ __launch_bounds__(256)
void sparkRows(const float* __restrict__ W, const float* __restrict__ s,
               const unsigned int* __restrict__ visited, const float* __restrict__ noise,
               const int* __restrict__ spark_pos, const float* __restrict__ energy,
               const int* __restrict__ age, const unsigned int* __restrict__ active,
               const float* __restrict__ u_main, const float* __restrict__ u_branch,
               float* __restrict__ outW, float* __restrict__ outS, float* __restrict__ outV)
{
    const int sp = blockIdx.x;
    if (active[sp] == 0u) return;
    const int row = spark_pos[sp];
    for (int t = 0; t < sp; ++t)
        if (active[t] != 0u && spark_pos[t] == row) return;   // earlier spark owns row
    const int tid = threadIdx.x;
    const size_t rowOff = (size_t)row * NN;

    __shared__ float  m_add[SS];   // 0.02f * energy
    __shared__ int    m_u[SS];     // spark index (u_main / u_branch row)
    __shared__ int    m_main[SS];  // sampled transition per match
    __shared__ int    s_cnt, s_force;
    __shared__ double part[SS];
    __shared__ int    ired[SS];
    __shared__ float  red[SS];

    if (tid == 0) {
        int c = 0, f = 0;
        for (int u = sp; u < SS; ++u)
            if (active[u] != 0u && spark_pos[u] == row) {
                m_add[c] = 0.02f * energy[u];
                m_u[c]   = u;
                if (age[u] < 5) f = 1;
                ++c;
            }
        s_cnt = c; s_force = f;
    }
    __syncthreads();
    const int nMatch = s_cnt;

    // Pass A: contiguous chunks — matvec partial + f64 CDF prefix (ordered).
    const float* __restrict__ Wrow = W + rowOff;
    const int base = tid * 32;
    float  acc  = 0.0f;
    double lsum = 0.0;
    for (int k = 0; k < 32; ++k) {
        const float wval = Wrow[base + k];
        acc  += wval * (0.95f * s[base + k]);
        lsum += (double)(fmaxf(wval, 0.0f) + 1e-6f);
    }
    part[tid] = lsum;
    __syncthreads();
    for (int off = 1; off < 256; off <<= 1) {       // Hillis-Steele inclusive scan
        const double v = (tid >= off) ? part[tid - off] : 0.0;
        __syncthreads();
        part[tid] += v;
        __syncthreads();
    }
    const double total = part[255];
    const double excl  = (tid == 0) ? 0.0 : part[tid - 1];

    for (int m = 0; m < nMatch; ++m) {              // inverse-CDF sample per match
        const double thr = (double)u_main[m_u[m]] * total;  // cdf[j]<u <=> prefix[j]<u*total
        double run = excl;
        int cnt = 0;
        for (int k = 0; k < 32; ++k) {
            run += (double)(fmaxf(Wrow[base + k], 0.0f) + 1e-6f);
            cnt += (run < thr) ? 1 : 0;
        }
        ired[tid] = cnt;
        __syncthreads();
        for (int off = 128; off > 0; off >>= 1) {
            if (tid < off) ired[tid] += ired[tid + off];
            __syncthreads();
        }
        if (tid == 0) m_main[m] = min(ired[0], NN - 1);
        __syncthreads();
    }

    // Pass B: apply path-reinforcement + branch + decay + clamp + visited.
    const f4*  __restrict__ W4 = reinterpret_cast<const f4*>(W + rowOff);
    const ui4* __restrict__ V4 = reinterpret_cast<const ui4*>(visited + rowOff);
    f4* __restrict__ oW = reinterpret_cast<f4*>(outW + rowOff);
    f4* __restrict__ oV = reinterpret_cast<f4*>(outV + rowOff);
    for (int i = 0; i < 8; ++i) {
        const int idx = i * 256 + tid;
        const f4  w = W4[idx];
        const ui4 v = V4[idx];
        const float wf[4] = {w.x, w.y, w.z, w.w};
        const unsigned int vf[4] = {v.x, v.y, v.z, v.w};
        float ow[4], ov[4];
        const int jb = idx * 4;
#pragma unroll
        for (int c = 0; c < 4; ++c) {
            const int j = jb + c;
            const float wval = wf[c];
            const float pvv  = fmaxf(wval, 0.0f) + 1e-6f;    // pre-update positive
            float wt  = wval;
            bool  hit = false;
            for (int k = 0; k < nMatch; ++k) {
                float cts = 0.0f;
                if (j == m_main[k]) cts += 1.0f;
                if (pvv > 0.6f) {
                    if (u_branch[(size_t)m_u[k] * NN + j] < 0.3f) cts += 1.0f;
                }
                if (cts != 0.0f) { hit = true; wt += m_add[k] * cts; }
            }
            const bool vis = (vf[c] != 0u) || hit;
            ow[c] = decay_clamp(wt, vis);
            ov[c] = vis ? 1.0f : 0.0f;
        }
        f4 owv, ovv;
        owv.x = ow[0]; owv.y = ow[1]; owv.z = ow[2]; owv.w = ow[3];
        ovv.x = ov[0]; ovv.y = ov[1]; ovv.z = ov[2]; ovv.w = ov[3];
        __builtin_nontemporal_store(owv, oW + idx);
        __builtin_nontemporal_store(ovv, oV + idx);
    }

    // s_new[row]
    red[tid] = acc;
    __syncthreads();
    for (int off = 128; off > 0; off >>= 1) {
        if (tid < off) red[tid] += red[tid + off];
        __syncthreads();
    }
    if (tid == 0) {
        const float y = red[0] + 0.05f * noise[row];
        outS[row] = (s_force != 0) ? 1.0f : (1.0f / (1.0f + expf(-y)));
    }
}

// ---------------------------------------------------------------------------
extern "C" void kernel_launch(void* const* d_in, const int* in_sizes, int n_in,
                              void* d_out, int out_size, void* d_ws, size_t ws_size,
                              hipStream_t stream) {
    const float*        W         = (const float*)d_in[0];
    const float*        s         = (const float*)d_in[1];
    const unsigned int* visited   = (const unsigned int*)d_in[2];  // bool as int32
    const float*        noise     = (const float*)d_in[3];
    const int*          spark_pos = (const int*)d_in[4];
    const float*        energy    = (const float*)d_in[5];
    const int*          age       = (const int*)d_in[6];
    const unsigned int* active    = (const unsigned int*)d_in[7];  // bool as int32
    const float*        u_main    = (const float*)d_in[8];
    const float*        u_branch  = (const float*)d_in[9];

    float* outW = (float*)d_out;                  // [N*N]
    float* outS = outW + (size_t)NN * NN;         // [N]
    float* outV = outS + NN;                      // [N*N] (bool as float32)

    (void)d_ws; (void)ws_size;                    // workspace intentionally unused

    fastRows <<<NN, 256, 0, stream>>>(W, s, visited, noise, spark_pos, active,
                                      outW, outS, outV);
    sparkRows<<<SS, 256, 0, stream>>>(W, s, visited, noise, spark_pos, energy,
                                      age, active, u_main, u_branch,
                                      outW, outS, outV);
}

// Round 4
// 196.761 us; speedup vs baseline: 1.1318x; 1.1318x over previous
//
#include <hip/hip_runtime.h>

#define NN 8192
#define SS 256

typedef float        f4  __attribute__((ext_vector_type(4)));
typedef unsigned int ui4 __attribute__((ext_vector_type(4)));

// decay constants: float(1 - 0.001*0.02) and float(1 - 0.001)
__device__ __forceinline__ float decay_clamp(float w, bool vis) {
    const float d = vis ? 0.99998f : 0.999f;
    const float x = w * d;
    return fminf(fmaxf(x, -2.0f), 2.0f);
}

// One block per row. Fully self-contained: no workspace, no cross-kernel state.
// Every element of outW/outV/outS is written unconditionally each call.
// Identical to the round-2 kernel EXCEPT: output stores are nontemporal.
__global__ __launch_bounds__(256)
void fusedSpark(const float* __restrict__ W, const float* __restrict__ s,
                const unsigned int* __restrict__ visited, const float* __restrict__ noise,
                const int* __restrict__ spark_pos, const float* __restrict__ energy,
                const int* __restrict__ age, const unsigned int* __restrict__ active,
                const float* __restrict__ u_main, const float* __restrict__ u_branch,
                float* __restrict__ outW, float* __restrict__ outS, float* __restrict__ outV)
{
    const int row  = blockIdx.x;
    const int tid  = threadIdx.x;
    const int lane = tid & 63;
    const int wv   = tid >> 6;
    const size_t rowOff = (size_t)row * NN;

    // ---- find active sparks on this row (deterministic, ordered by spark idx) ----
    __shared__ unsigned long long wmask[4];
    __shared__ int   s_force;
    __shared__ float m_add[SS];   // 0.02f * energy
    __shared__ int   m_u[SS];     // spark index (u_main / u_branch row)
    __shared__ int   m_main[SS];  // sampled main_next per match
    __shared__ double part[SS];
    __shared__ int    ired[SS];
    __shared__ float  red[SS];

    const bool match = (active[tid] != 0u) && (spark_pos[tid] == row);
    const unsigned long long bal = __ballot(match);
    if (lane == 0) wmask[wv] = bal;
    if (tid == 0)  s_force = 0;
    __syncthreads();
    if (match && age[tid] < 5) atomicOr(&s_force, 1);   // benign: all write 1
    int nMatch = 0;
#pragma unroll
    for (int w = 0; w < 4; ++w) nMatch += __popcll(wmask[w]);
    if (match) {
        int rank = __popcll(bal & ((1ull << lane) - 1ull));
        for (int w = 0; w < wv; ++w) rank += __popcll(wmask[w]);
        m_add[rank] = 0.02f * energy[tid];
        m_u[rank]   = tid;
    }
    __syncthreads();

    float acc = 0.0f;

    if (nMatch == 0) {
        // ---- fast path: fused matvec + decay + clamp + visited copy ----
        const f4*  __restrict__ W4 = reinterpret_cast<const f4*>(W + rowOff);
        const ui4* __restrict__ V4 = reinterpret_cast<const ui4*>(visited + rowOff);
        const f4*  __restrict__ s4 = reinterpret_cast<const f4*>(s);
        f4* __restrict__ oW = reinterpret_cast<f4*>(outW + rowOff);
        f4* __restrict__ oV = reinterpret_cast<f4*>(outV + rowOff);
#pragma unroll
        for (int i = 0; i < 8; ++i) {
            const int idx = i * 256 + tid;       // coalesced float4 index
            const f4  w  = W4[idx];
            const ui4 v  = V4[idx];
            const f4  sv = s4[idx];
            acc += w.x * (0.95f * sv.x);
            acc += w.y * (0.95f * sv.y);
            acc += w.z * (0.95f * sv.z);
            acc += w.w * (0.95f * sv.w);
            f4 ow, ov;
            ow.x = decay_clamp(w.x, v.x != 0u); ov.x = (v.x != 0u) ? 1.0f : 0.0f;
            ow.y = decay_clamp(w.y, v.y != 0u); ov.y = (v.y != 0u) ? 1.0f : 0.0f;
            ow.z = decay_clamp(w.z, v.z != 0u); ov.z = (v.z != 0u) ? 1.0f : 0.0f;
            ow.w = decay_clamp(w.w, v.w != 0u); ov.w = (v.w != 0u) ? 1.0f : 0.0f;
            __builtin_nontemporal_store(ow, oW + idx);
            __builtin_nontemporal_store(ov, oV + idx);
        }
    } else {
        // ---- spark row (<=256 rows total) ----
        // Pass A: contiguous chunks for ordered CDF prefix (f64) + matvec partial.
        const float* __restrict__ Wrow = W + rowOff;
        const int base = tid * 32;
        double lsum = 0.0;
        for (int k = 0; k < 32; ++k) {
            const float wval = Wrow[base + k];
            acc  += wval * (0.95f * s[base + k]);
            lsum += (double)(fmaxf(wval, 0.0f) + 1e-6f);
        }
        part[tid] = lsum;
        __syncthreads();
        for (int off = 1; off < 256; off <<= 1) {      // Hillis-Steele inclusive scan
            const double v = (tid >= off) ? part[tid - off] : 0.0;
            __syncthreads();
            part[tid] += v;
            __syncthreads();
        }
        const double total = part[255];
        const double excl  = (tid == 0) ? 0.0 : part[tid - 1];

        for (int m = 0; m < nMatch; ++m) {             // sample main_next per match
            const double thr = (double)u_main[m_u[m]] * total;  // cdf[j] < u  <=>  prefix[j] < u*total
            double run = excl;
            int cnt = 0;
            for (int k = 0; k < 32; ++k) {
                run += (double)(fmaxf(Wrow[base + k], 0.0f) + 1e-6f);
                cnt += (run < thr) ? 1 : 0;
            }
            ired[tid] = cnt;
            __syncthreads();
            for (int off = 128; off > 0; off >>= 1) {
                if (tid < off) ired[tid] += ired[tid + off];
                __syncthreads();
            }
            if (tid == 0) m_main[m] = min(ired[0], NN - 1);
            __syncthreads();
        }

        // Pass B: strided apply (adds + branch + decay + clamp + visited).
        const f4*  __restrict__ W4 = reinterpret_cast<const f4*>(W + rowOff);
        const ui4* __restrict__ V4 = reinterpret_cast<const ui4*>(visited + rowOff);
        f4* __restrict__ oW = reinterpret_cast<f4*>(outW + rowOff);
        f4* __restrict__ oV = reinterpret_cast<f4*>(outV + rowOff);
        for (int i = 0; i < 8; ++i) {
            const int idx = i * 256 + tid;
            const f4  w = W4[idx];
            const ui4 v = V4[idx];
            const float wf[4] = {w.x, w.y, w.z, w.w};
            const unsigned int vf[4] = {v.x, v.y, v.z, v.w};
            float ow[4], ov[4];
            const int jb = idx * 4;
#pragma unroll
            for (int c = 0; c < 4; ++c) {
                const int j = jb + c;
                const float wval = wf[c];
                const float pvv  = fmaxf(wval, 0.0f) + 1e-6f;   // pre-update positive
                float wt  = wval;
                bool  hit = false;
                for (int k = 0; k < nMatch; ++k) {
                    float cts = 0.0f;
                    if (j == m_main[k]) cts += 1.0f;
                    if (pvv > 0.6f) {                            // branch: z>6 => ~never
                        if (u_branch[(size_t)m_u[k] * NN + j] < 0.3f) cts += 1.0f;
                    }
                    if (cts != 0.0f) { hit = true; wt += m_add[k] * cts; }
                }
                const bool vis = (vf[c] != 0u) || hit;
                ow[c] = decay_clamp(wt, vis);
                ov[c] = vis ? 1.0f : 0.0f;
            }
            f4 owv, ovv;
            owv.x = ow[0]; owv.y = ow[1]; owv.z = ow[2]; owv.w = ow[3];
            ovv.x = ov[0]; ovv.y = ov[1]; ovv.z = ov[2]; ovv.w = ov[3];
            __builtin_nontemporal_store(owv, oW + idx);
            __builtin_nontemporal_store(ovv, oV + idx);
        }
    }

    // ---- s_new[row]: block reduction + sigmoid + force override ----
    red[tid] = acc;
    __syncthreads();
    for (int off = 128; off > 0; off >>= 1) {
        if (tid < off) red[tid] += red[tid + off];
        __syncthreads();
    }
    if (tid == 0) {
        const float y = red[0] + 0.05f * noise[row];
        outS[row] = (s_force != 0) ? 1.0f : (1.0f / (1.0f + expf(-y)));
    }
}

// ---------------------------------------------------------------------------
extern "C" void kernel_launch(void* const* d_in, const int* in_sizes, int n_in,
                              void* d_out, int out_size, void* d_ws, size_t ws_size,
                              hipStream_t stream) {
    const float*        W         = (const float*)d_in[0];
    const float*        s         = (const float*)d_in[1];
    const unsigned int* visited   = (const unsigned int*)d_in[2];  // bool as int32
    const float*        noise     = (const float*)d_in[3];
    const int*          spark_pos = (const int*)d_in[4];
    const float*        energy    = (const float*)d_in[5];
    const int*          age       = (const int*)d_in[6];
    const unsigned int* active    = (const unsigned int*)d_in[7];  // bool as int32
    const float*        u_main    = (const float*)d_in[8];
    const float*        u_branch  = (const float*)d_in[9];

    float* outW = (float*)d_out;                  // [N*N]
    float* outS = outW + (size_t)NN * NN;         // [N]
    float* outV = outS + NN;                      // [N*N] (bool as float32)

    (void)d_ws; (void)ws_size;                    // workspace intentionally unused

    fusedSpark<<<NN, 256, 0, stream>>>(W, s, visited, noise, spark_pos, energy,
                                       age, active, u_main, u_branch,
                                       outW, outS, outV);
}

// Round 6
// 187.918 us; speedup vs baseline: 1.1851x; 1.0471x over previous
//
#include <hip/hip_runtime.h>

#define NN 8192
#define SS 256

typedef float        f4  __attribute__((ext_vector_type(4)));
typedef unsigned int ui4 __attribute__((ext_vector_type(4)));

// decay constants: float(1 - 0.001*0.02) and float(1 - 0.001)
__device__ __forceinline__ float decay_clamp(float w, bool vis) {
    const float d = vis ? 0.99998f : 0.999f;
    const float x = w * d;
    return fminf(fmaxf(x, -2.0f), 2.0f);
}

// One block per row. Fully self-contained: no workspace, no cross-kernel state.
// Every element of outW/outV/outS is written unconditionally each call.
// Round-4 kernel + ONE change: nontemporal LOADS on the W / visited streams.
__global__ __launch_bounds__(256)
void fusedSpark(const float* __restrict__ W, const float* __restrict__ s,
                const unsigned int* __restrict__ visited, const float* __restrict__ noise,
                const int* __restrict__ spark_pos, const float* __restrict__ energy,
                const int* __restrict__ age, const unsigned int* __restrict__ active,
                const float* __restrict__ u_main, const float* __restrict__ u_branch,
                float* __restrict__ outW, float* __restrict__ outS, float* __restrict__ outV)
{
    const int row  = blockIdx.x;
    const int tid  = threadIdx.x;
    const int lane = tid & 63;
    const int wv   = tid >> 6;
    const size_t rowOff = (size_t)row * NN;

    // ---- find active sparks on this row (deterministic, ordered by spark idx) ----
    __shared__ unsigned long long wmask[4];
    __shared__ int   s_force;
    __shared__ float m_add[SS];   // 0.02f * energy
    __shared__ int   m_u[SS];     // spark index (u_main / u_branch row)
    __shared__ int   m_main[SS];  // sampled main_next per match
    __shared__ double part[SS];
    __shared__ int    ired[SS];
    __shared__ float  red[SS];

    const bool match = (active[tid] != 0u) && (spark_pos[tid] == row);
    const unsigned long long bal = __ballot(match);
    if (lane == 0) wmask[wv] = bal;
    if (tid == 0)  s_force = 0;
    __syncthreads();
    if (match && age[tid] < 5) atomicOr(&s_force, 1);   // benign: all write 1
    int nMatch = 0;
#pragma unroll
    for (int w = 0; w < 4; ++w) nMatch += __popcll(wmask[w]);
    if (match) {
        int rank = __popcll(bal & ((1ull << lane) - 1ull));
        for (int w = 0; w < wv; ++w) rank += __popcll(wmask[w]);
        m_add[rank] = 0.02f * energy[tid];
        m_u[rank]   = tid;
    }
    __syncthreads();

    float acc = 0.0f;

    if (nMatch == 0) {
        // ---- fast path: fused matvec + decay + clamp + visited copy ----
        const f4*  __restrict__ W4 = reinterpret_cast<const f4*>(W + rowOff);
        const ui4* __restrict__ V4 = reinterpret_cast<const ui4*>(visited + rowOff);
        const f4*  __restrict__ s4 = reinterpret_cast<const f4*>(s);
        f4* __restrict__ oW = reinterpret_cast<f4*>(outW + rowOff);
        f4* __restrict__ oV = reinterpret_cast<f4*>(outV + rowOff);
#pragma unroll
        for (int i = 0; i < 8; ++i) {
            const int idx = i * 256 + tid;       // coalesced float4 index
            const f4  w  = __builtin_nontemporal_load(W4 + idx);  // streamed once
            const ui4 v  = __builtin_nontemporal_load(V4 + idx);  // streamed once
            const f4  sv = s4[idx];                               // reused: keep cached
            acc += w.x * (0.95f * sv.x);
            acc += w.y * (0.95f * sv.y);
            acc += w.z * (0.95f * sv.z);
            acc += w.w * (0.95f * sv.w);
            f4 ow, ov;
            ow.x = decay_clamp(w.x, v.x != 0u); ov.x = (v.x != 0u) ? 1.0f : 0.0f;
            ow.y = decay_clamp(w.y, v.y != 0u); ov.y = (v.y != 0u) ? 1.0f : 0.0f;
            ow.z = decay_clamp(w.z, v.z != 0u); ov.z = (v.z != 0u) ? 1.0f : 0.0f;
            ow.w = decay_clamp(w.w, v.w != 0u); ov.w = (v.w != 0u) ? 1.0f : 0.0f;
            __builtin_nontemporal_store(ow, oW + idx);
            __builtin_nontemporal_store(ov, oV + idx);
        }
    } else {
        // ---- spark row (<=256 rows total) ----
        // Pass A: contiguous chunks for ordered CDF prefix (f64) + matvec partial.
        const float* __restrict__ Wrow = W + rowOff;
        const int base = tid * 32;
        double lsum = 0.0;
        for (int k = 0; k < 32; ++k) {
            const float wval = Wrow[base + k];
            acc  += wval * (0.95f * s[base + k]);
            lsum += (double)(fmaxf(wval, 0.0f) + 1e-6f);
        }
        part[tid] = lsum;
        __syncthreads();
        for (int off = 1; off < 256; off <<= 1) {      // Hillis-Steele inclusive scan
            const double v = (tid >= off) ? part[tid - off] : 0.0;
            __syncthreads();
            part[tid] += v;
            __syncthreads();
        }
        const double total = part[255];
        const double excl  = (tid == 0) ? 0.0 : part[tid - 1];

        for (int m = 0; m < nMatch; ++m) {             // sample main_next per match
            const double thr = (double)u_main[m_u[m]] * total;  // cdf[j] < u  <=>  prefix[j] < u*total
            double run = excl;
            int cnt = 0;
            for (int k = 0; k < 32; ++k) {
                run += (double)(fmaxf(Wrow[base + k], 0.0f) + 1e-6f);
                cnt += (run < thr) ? 1 : 0;
            }
            ired[tid] = cnt;
            __syncthreads();
            for (int off = 128; off > 0; off >>= 1) {
                if (tid < off) ired[tid] += ired[tid + off];
                __syncthreads();
            }
            if (tid == 0) m_main[m] = min(ired[0], NN - 1);
            __syncthreads();
        }

        // Pass B: strided apply (adds + branch + decay + clamp + visited).
        const f4*  __restrict__ W4 = reinterpret_cast<const f4*>(W + rowOff);
        const ui4* __restrict__ V4 = reinterpret_cast<const ui4*>(visited + rowOff);
        f4* __restrict__ oW = reinterpret_cast<f4*>(outW + rowOff);
        f4* __restrict__ oV = reinterpret_cast<f4*>(outV + rowOff);
        for (int i = 0; i < 8; ++i) {
            const int idx = i * 256 + tid;
            const f4  w = W4[idx];
            const ui4 v = V4[idx];
            const float wf[4] = {w.x, w.y, w.z, w.w};
            const unsigned int vf[4] = {v.x, v.y, v.z, v.w};
            float ow[4], ov[4];
            const int jb = idx * 4;
#pragma unroll
            for (int c = 0; c < 4; ++c) {
                const int j = jb + c;
                const float wval = wf[c];
                const float pvv  = fmaxf(wval, 0.0f) + 1e-6f;   // pre-update positive
                float wt  = wval;
                bool  hit = false;
                for (int k = 0; k < nMatch; ++k) {
                    float cts = 0.0f;
                    if (j == m_main[k]) cts += 1.0f;
                    if (pvv > 0.6f) {                            // branch: z>6 => ~never
                        if (u_branch[(size_t)m_u[k] * NN + j] < 0.3f) cts += 1.0f;
                    }
                    if (cts != 0.0f) { hit = true; wt += m_add[k] * cts; }
                }
                const bool vis = (vf[c] != 0u) || hit;
                ow[c] = decay_clamp(wt, vis);
                ov[c] = vis ? 1.0f : 0.0f;
            }
            f4 owv, ovv;
            owv.x = ow[0]; owv.y = ow[1]; owv.z = ow[2]; owv.w = ow[3];
            ovv.x = ov[0]; ovv.y = ov[1]; ovv.z = ov[2]; ovv.w = ov[3];
            __builtin_nontemporal_store(owv, oW + idx);
            __builtin_nontemporal_store(ovv, oV + idx);
        }
    }

    // ---- s_new[row]: block reduction + sigmoid + force override ----
    red[tid] = acc;
    __syncthreads();
    for (int off = 128; off > 0; off >>= 1) {
        if (tid < off) red[tid] += red[tid + off];
        __syncthreads();
    }
    if (tid == 0) {
        const float y = red[0] + 0.05f * noise[row];
        outS[row] = (s_force != 0) ? 1.0f : (1.0f / (1.0f + expf(-y)));
    }
}

// ---------------------------------------------------------------------------
extern "C" void kernel_launch(void* const* d_in, const int* in_sizes, int n_in,
                              void* d_out, int out_size, void* d_ws, size_t ws_size,
                              hipStream_t stream) {
    const float*        W         = (const float*)d_in[0];
    const float*        s         = (const float*)d_in[1];
    const unsigned int* visited   = (const unsigned int*)d_in[2];  // bool as int32
    const float*        noise     = (const float*)d_in[3];
    const int*          spark_pos = (const int*)d_in[4];
    const float*        energy    = (const float*)d_in[5];
    const int*          age       = (const int*)d_in[6];
    const unsigned int* active    = (const unsigned int*)d_in[7];  // bool as int32
    const float*        u_main    = (const float*)d_in[8];
    const float*        u_branch  = (const float*)d_in[9];

    float* outW = (float*)d_out;                  // [N*N]
    float* outS = outW + (size_t)NN * NN;         // [N]
    float* outV = outS + NN;                      // [N*N] (bool as float32)

    (void)d_ws; (void)ws_size;                    // workspace intentionally unused

    fusedSpark<<<NN, 256, 0, stream>>>(W, s, visited, noise, spark_pos, energy,
                                       age, active, u_main, u_branch,
                                       outW, outS, outV);
}